// Round 6
// baseline (73.798 us; speedup 1.0000x reference)
//
#include <hip/hip_runtime.h>

// vol [2,160,192,160,1] f32, trf [2,160,192,160,3] f32
constexpr int B = 2, X = 160, Y = 192, Z = 160;
constexpr int N = B * X * Y * Z;      // 9,830,400 = 38400 * 256 exactly
constexpr int NBLK = N / 256;         // 38400, divisible by 8
constexpr int NXCD = 8;
constexpr int CHUNK = NBLK / NXCD;    // 4800

typedef float f32x2 __attribute__((ext_vector_type(2), aligned(4)));

__global__ __launch_bounds__(256) void warp_kernel(
    const float* __restrict__ vol,
    const float* __restrict__ trf,
    float* __restrict__ out)
{
    __shared__ float s[768];          // 256 voxels x 3 displacement floats

    const int tid = threadIdx.x;

    // XCD-chunked bijective swizzle: hardware assigns blockIdx round-robin
    // to XCDs (bid % 8); give each XCD a contiguous 1/8 of the volume so
    // co-resident blocks on a CU are spatial neighbors (L1/L2 locality).
    const int bid = blockIdx.x;
    const int eff = (bid & (NXCD - 1)) * CHUNK + (bid >> 3);
    const size_t base = (size_t)eff * 256;          // first voxel of block

    // coalesced, nontemporal load of this block's 768 consecutive trf floats
    const float* tf = trf + base * 3;
    s[tid]       = __builtin_nontemporal_load(tf + tid);
    s[tid + 256] = __builtin_nontemporal_load(tf + tid + 256);
    s[tid + 512] = __builtin_nontemporal_load(tf + tid + 512);
    __syncthreads();

    const float dx = s[3 * tid + 0];
    const float dy = s[3 * tid + 1];
    const float dz = s[3 * tid + 2];

    const int idx = (int)base + tid;

    // decompose idx -> (b, x, y, z), z innermost
    int z  = idx % Z;
    int t  = idx / Z;
    int y  = t % Y;
    int t2 = t / Y;
    int x  = t2 % X;
    int b  = t2 / X;

    float lx = (float)x + dx;
    float ly = (float)y + dy;
    float lz = (float)z + dz;

    // reference semantics: l0=clip(floor(l),0,max); l1=clip(l0+1,0,max);
    // cl=clip(l,0,max); weight(corner0)=l1-cl; weight(corner1)=1-(l1-cl)
    const float mx = (float)(X - 1), my = (float)(Y - 1), mz = (float)(Z - 1);

    float lx0 = fminf(fmaxf(floorf(lx), 0.0f), mx);
    float lx1 = fminf(lx0 + 1.0f, mx);
    float clx = fminf(fmaxf(lx, 0.0f), mx);
    float wxA = lx1 - clx, wxB = 1.0f - wxA;
    int ix0 = (int)lx0, ix1 = (int)lx1;

    float ly0 = fminf(fmaxf(floorf(ly), 0.0f), my);
    float ly1 = fminf(ly0 + 1.0f, my);
    float cly = fminf(fmaxf(ly, 0.0f), my);
    float wyA = ly1 - cly, wyB = 1.0f - wyA;
    int iy0 = (int)ly0, iy1 = (int)ly1;

    float lz0 = fminf(fmaxf(floorf(lz), 0.0f), mz);
    float lz1 = fminf(lz0 + 1.0f, mz);
    float clz = fminf(fmaxf(lz, 0.0f), mz);
    float wzA = lz1 - clz, wzB = 1.0f - wzA;
    int iz0 = (int)lz0;

    // z-pair gather: one 8B load covers both z corners.
    // pz = min(iz0, Z-2); iz0==pz ? (v0,v1)=(p.x,p.y) : (v0,v1)=(p.y,p.y)
    int pz = min(iz0, Z - 2);
    bool hi = (iz0 != pz);

    int bX = b * X;
    size_t base00 = ((size_t)(bX + ix0) * Y + iy0) * Z + pz;
    size_t base01 = ((size_t)(bX + ix0) * Y + iy1) * Z + pz;
    size_t base10 = ((size_t)(bX + ix1) * Y + iy0) * Z + pz;
    size_t base11 = ((size_t)(bX + ix1) * Y + iy1) * Z + pz;

    f32x2 p00 = *reinterpret_cast<const f32x2*>(vol + base00);
    f32x2 p01 = *reinterpret_cast<const f32x2*>(vol + base01);
    f32x2 p10 = *reinterpret_cast<const f32x2*>(vol + base10);
    f32x2 p11 = *reinterpret_cast<const f32x2*>(vol + base11);

    float v000 = hi ? p00.y : p00.x, v001 = p00.y;
    float v010 = hi ? p01.y : p01.x, v011 = p01.y;
    float v100 = hi ? p10.y : p10.x, v111_ = p11.y;
    float v110 = hi ? p11.y : p11.x;
    float v101 = p10.y;
    float v111 = v111_;

    float r = wxA * (wyA * (wzA * v000 + wzB * v001) +
                     wyB * (wzA * v010 + wzB * v011)) +
              wxB * (wyA * (wzA * v100 + wzB * v101) +
                     wyB * (wzA * v110 + wzB * v111));

    __builtin_nontemporal_store(r, out + idx);
}

extern "C" void kernel_launch(void* const* d_in, const int* in_sizes, int n_in,
                              void* d_out, int out_size, void* d_ws, size_t ws_size,
                              hipStream_t stream) {
    const float* vol = (const float*)d_in[0];
    const float* trf = (const float*)d_in[1];
    float* out = (float*)d_out;

    warp_kernel<<<NBLK, 256, 0, stream>>>(vol, trf, out);
}

// Round 7
// 69.933 us; speedup vs baseline: 1.0553x; 1.0553x over previous
//
#include <hip/hip_runtime.h>

// vol [2,160,192,160,1] f32, trf [2,160,192,160,3] f32
constexpr int B = 2, X = 160, Y = 192, Z = 160;
constexpr int XT = X / 4, YT = Y / 8, ZT = Z / 8;   // 40, 24, 20 tiles per dim
constexpr int NTILES = B * XT * YT * ZT;            // 38400, divisible by 8
constexpr int NXCD = 8;
constexpr int CHUNK = NTILES / NXCD;                // 4800

typedef float f32x2 __attribute__((ext_vector_type(2), aligned(4)));

__global__ __launch_bounds__(256) void warp_kernel(
    const float* __restrict__ vol,
    const float* __restrict__ trf,
    float* __restrict__ out)
{
    const int tid = threadIdx.x;
    const int bid = blockIdx.x;

    // XCD-chunked bijective swizzle (NTILES % 8 == 0)
    const int eff = (bid & (NXCD - 1)) * CHUNK + (bid >> 3);

    // tile id -> (b, tx, ty, tz), tz fastest (consecutive tiles are z-neighbors)
    int tz = eff % ZT;
    int r  = eff / ZT;
    int ty = r % YT;
    int r2 = r / YT;
    int tx = r2 % XT;
    int b  = r2 / XT;

    // thread -> 4x8x8 tile coords; wave (64 threads) = one x-slice (8y x 8z)
    int lz = tid & 7;
    int ly = (tid >> 3) & 7;
    int lx = tid >> 6;

    int x = tx * 4 + lx;
    int y = ty * 8 + ly;
    int z = tz * 8 + lz;

    const int idx = ((b * X + x) * Y + y) * Z + z;

    const float dx = trf[(size_t)idx * 3 + 0];
    const float dy = trf[(size_t)idx * 3 + 1];
    const float dz = trf[(size_t)idx * 3 + 2];

    float lxf = (float)x + dx;
    float lyf = (float)y + dy;
    float lzf = (float)z + dz;

    // reference semantics: l0=clip(floor(l),0,max); l1=clip(l0+1,0,max);
    // cl=clip(l,0,max); weight(corner0)=l1-cl; weight(corner1)=1-(l1-cl)
    const float mx = (float)(X - 1), my = (float)(Y - 1), mz = (float)(Z - 1);

    float lx0 = fminf(fmaxf(floorf(lxf), 0.0f), mx);
    float lx1 = fminf(lx0 + 1.0f, mx);
    float clx = fminf(fmaxf(lxf, 0.0f), mx);
    float wxA = lx1 - clx, wxB = 1.0f - wxA;
    int ix0 = (int)lx0, ix1 = (int)lx1;

    float ly0 = fminf(fmaxf(floorf(lyf), 0.0f), my);
    float ly1 = fminf(ly0 + 1.0f, my);
    float cly = fminf(fmaxf(lyf, 0.0f), my);
    float wyA = ly1 - cly, wyB = 1.0f - wyA;
    int iy0 = (int)ly0, iy1 = (int)ly1;

    float lz0 = fminf(fmaxf(floorf(lzf), 0.0f), mz);
    float lz1 = fminf(lz0 + 1.0f, mz);
    float clz = fminf(fmaxf(lzf, 0.0f), mz);
    float wzA = lz1 - clz, wzB = 1.0f - wzA;
    int iz0 = (int)lz0;

    // z-pair gather: one 8B load covers both z corners.
    int pz = min(iz0, Z - 2);
    bool hi = (iz0 != pz);

    // strength-reduced corner bases
    size_t base00 = ((size_t)(b * X + ix0) * Y + iy0) * Z + pz;
    int dyZ  = (iy1 - iy0) * Z;          // 0 or Z
    int dxYZ = (ix1 - ix0) * (Y * Z);    // 0 or Y*Z
    size_t base01 = base00 + dyZ;
    size_t base10 = base00 + dxYZ;
    size_t base11 = base10 + dyZ;

    f32x2 p00 = *reinterpret_cast<const f32x2*>(vol + base00);
    f32x2 p01 = *reinterpret_cast<const f32x2*>(vol + base01);
    f32x2 p10 = *reinterpret_cast<const f32x2*>(vol + base10);
    f32x2 p11 = *reinterpret_cast<const f32x2*>(vol + base11);

    float v000 = hi ? p00.y : p00.x, v001 = p00.y;
    float v010 = hi ? p01.y : p01.x, v011 = p01.y;
    float v100 = hi ? p10.y : p10.x, v101 = p10.y;
    float v110 = hi ? p11.y : p11.x, v111 = p11.y;

    float res = wxA * (wyA * (wzA * v000 + wzB * v001) +
                       wyB * (wzA * v010 + wzB * v011)) +
                wxB * (wyA * (wzA * v100 + wzB * v101) +
                       wyB * (wzA * v110 + wzB * v111));

    __builtin_nontemporal_store(res, out + idx);
}

extern "C" void kernel_launch(void* const* d_in, const int* in_sizes, int n_in,
                              void* d_out, int out_size, void* d_ws, size_t ws_size,
                              hipStream_t stream) {
    const float* vol = (const float*)d_in[0];
    const float* trf = (const float*)d_in[1];
    float* out = (float*)d_out;

    warp_kernel<<<NTILES, 256, 0, stream>>>(vol, trf, out);
}

// Round 8
// 61.001 us; speedup vs baseline: 1.2098x; 1.1464x over previous
//
#include <hip/hip_runtime.h>

// vol [2,160,192,160,1] f32, trf [2,160,192,160,3] f32
constexpr int B = 2, X = 160, Y = 192, Z = 160;
constexpr int TX = 4, TY = 4, TZ = 16;              // tile shape
constexpr int XT = X / TX, YT = Y / TY, ZT = Z / TZ; // 40, 48, 10
constexpr int NTILES = B * XT * YT * ZT;            // 38400, divisible by 8
constexpr int NXCD = 8;
constexpr int CHUNK = NTILES / NXCD;                // 4800

typedef float f32x2 __attribute__((ext_vector_type(2), aligned(4)));

__global__ __launch_bounds__(256) void warp_kernel(
    const float* __restrict__ vol,
    const float* __restrict__ trf,
    float* __restrict__ out)
{
    const int tid = threadIdx.x;
    const int bid = blockIdx.x;

    // XCD-chunked bijective swizzle (NTILES % 8 == 0)
    const int eff = (bid & (NXCD - 1)) * CHUNK + (bid >> 3);

    // tile id -> (b, tx, ty, tz), tz fastest (consecutive tiles are z-neighbors)
    int tz = eff % ZT;
    int r  = eff / ZT;
    int ty = r % YT;
    int r2 = r / YT;
    int tx = r2 % XT;
    int b  = r2 / XT;

    // thread -> 4x4x16 tile coords; 16-lane groups are z-contiguous (64B lines)
    int lz = tid & 15;
    int ly = (tid >> 4) & 3;
    int lx = tid >> 6;

    int x = tx * TX + lx;
    int y = ty * TY + ly;
    int z = tz * TZ + lz;

    const int idx = ((b * X + x) * Y + y) * Z + z;

    const float dx = trf[(size_t)idx * 3 + 0];
    const float dy = trf[(size_t)idx * 3 + 1];
    const float dz = trf[(size_t)idx * 3 + 2];

    float lxf = (float)x + dx;
    float lyf = (float)y + dy;
    float lzf = (float)z + dz;

    // reference semantics: l0=clip(floor(l),0,max); l1=clip(l0+1,0,max);
    // cl=clip(l,0,max); weight(corner0)=l1-cl; weight(corner1)=1-(l1-cl)
    const float mx = (float)(X - 1), my = (float)(Y - 1), mz = (float)(Z - 1);

    float lx0 = fminf(fmaxf(floorf(lxf), 0.0f), mx);
    float lx1 = fminf(lx0 + 1.0f, mx);
    float clx = fminf(fmaxf(lxf, 0.0f), mx);
    float wxA = lx1 - clx, wxB = 1.0f - wxA;
    int ix0 = (int)lx0, ix1 = (int)lx1;

    float ly0 = fminf(fmaxf(floorf(lyf), 0.0f), my);
    float ly1 = fminf(ly0 + 1.0f, my);
    float cly = fminf(fmaxf(lyf, 0.0f), my);
    float wyA = ly1 - cly, wyB = 1.0f - wyA;
    int iy0 = (int)ly0, iy1 = (int)ly1;

    float lz0 = fminf(fmaxf(floorf(lzf), 0.0f), mz);
    float lz1 = fminf(lz0 + 1.0f, mz);
    float clz = fminf(fmaxf(lzf, 0.0f), mz);
    float wzA = lz1 - clz, wzB = 1.0f - wzA;
    int iz0 = (int)lz0;

    // z-pair gather: one 8B load covers both z corners.
    int pz = min(iz0, Z - 2);
    bool hi = (iz0 != pz);

    // strength-reduced corner bases
    size_t base00 = ((size_t)(b * X + ix0) * Y + iy0) * Z + pz;
    int dyZ  = (iy1 - iy0) * Z;          // 0 or Z
    int dxYZ = (ix1 - ix0) * (Y * Z);    // 0 or Y*Z
    size_t base01 = base00 + dyZ;
    size_t base10 = base00 + dxYZ;
    size_t base11 = base10 + dyZ;

    f32x2 p00 = *reinterpret_cast<const f32x2*>(vol + base00);
    f32x2 p01 = *reinterpret_cast<const f32x2*>(vol + base01);
    f32x2 p10 = *reinterpret_cast<const f32x2*>(vol + base10);
    f32x2 p11 = *reinterpret_cast<const f32x2*>(vol + base11);

    float v000 = hi ? p00.y : p00.x, v001 = p00.y;
    float v010 = hi ? p01.y : p01.x, v011 = p01.y;
    float v100 = hi ? p10.y : p10.x, v101 = p10.y;
    float v110 = hi ? p11.y : p11.x, v111 = p11.y;

    float res = wxA * (wyA * (wzA * v000 + wzB * v001) +
                       wyB * (wzA * v010 + wzB * v011)) +
                wxB * (wyA * (wzA * v100 + wzB * v101) +
                       wyB * (wzA * v110 + wzB * v111));

    out[idx] = res;
}

extern "C" void kernel_launch(void* const* d_in, const int* in_sizes, int n_in,
                              void* d_out, int out_size, void* d_ws, size_t ws_size,
                              hipStream_t stream) {
    const float* vol = (const float*)d_in[0];
    const float* trf = (const float*)d_in[1];
    float* out = (float*)d_out;

    warp_kernel<<<NTILES, 256, 0, stream>>>(vol, trf, out);
}

// Round 9
// 46.699 us; speedup vs baseline: 1.5803x; 1.3062x over previous
//
#include <hip/hip_runtime.h>

// vol [2,160,192,160,1] f32, trf [2,160,192,160,3] f32
constexpr int B = 2, X = 160, Y = 192, Z = 160;
constexpr int TXs = 8, TYs = 8, TZs = 16;                // output tile per block (1024 voxels)
constexpr int XT = X / TXs, YT = Y / TYs, ZT = Z / TZs;  // 20, 24, 10
constexpr int NTILES = B * XT * YT * ZT;                 // 9600, divisible by 8
constexpr int NXCD = 8;
constexpr int CHUNK = NTILES / NXCD;                     // 1200
// staged region: x,y halo +-4 (16 slots), z halo +-8 (32 slots) = 32 KB LDS
constexpr int RX = 16, RY = 16, RZ = 32;
constexpr int NROWS = RX * RY;                           // 256 rows (row = xi*16+yi)
constexpr int LDSF = NROWS * RZ;                         // 8192 floats

typedef float f32x4 __attribute__((ext_vector_type(4)));

__global__ __launch_bounds__(256) void warp_kernel(
    const float* __restrict__ vol,
    const float* __restrict__ trf,
    float* __restrict__ out)
{
    __shared__ float lds[LDSF];

    const int tid = threadIdx.x;
    const int bid = blockIdx.x;

    // XCD-chunked bijective swizzle (NTILES % 8 == 0)
    const int eff = (bid & (NXCD - 1)) * CHUNK + (bid >> 3);

    int tz = eff % ZT;
    int r  = eff / ZT;
    int ty = r % YT;
    int r2 = r / YT;
    int tx = r2 % XT;
    int b  = r2 / XT;

    const int xs = tx * TXs - 4;       // region x origin
    const int ys = ty * TYs - 4;       // region y origin
    const int zs = tz * TZs - 8;       // region z origin

    // ---- stage vol region into LDS (each 64B line walked once, coalesced) ----
    // 2048 f32x4 chunks; chunk c: row=c>>3 (xi=row>>4, yi=row&15), j=c&7 -> z=zs+4j
    // LDS slot chunk is XOR-swizzled: 4*(j ^ (row&7)) -- keeps 16B alignment,
    // spreads gather banks across y-rows.
#pragma unroll
    for (int k = 0; k < 8; ++k) {
        int c   = tid + k * 256;
        int row = c >> 3;
        int j   = c & 7;
        int xi  = row >> 4;
        int yi  = row & 15;
        int xg  = min(max(xs + xi, 0), X - 1);
        int yg  = min(max(ys + yi, 0), Y - 1);
        int zg  = min(max(zs + 4 * j, 0), Z - 4);
        const f32x4 v = *reinterpret_cast<const f32x4*>(
            vol + ((size_t)(b * X + xg) * Y + yg) * Z + zg);
        int slot = (row << 5) + ((j ^ (row & 7)) << 2);
        *reinterpret_cast<f32x4*>(&lds[slot]) = v;
    }
    __syncthreads();

    // ---- this thread's 4 voxels: (x, y, z0v..z0v+3) ----
    int zq = tid & 3;
    int ly = (tid >> 2) & 7;
    int lx = tid >> 5;
    int x  = tx * TXs + lx;
    int y  = ty * TYs + ly;
    int z0v = tz * TZs + 4 * zq;

    size_t vid0 = ((size_t)(b * X + x) * Y + y) * Z + z0v;

    const f32x4* tp = reinterpret_cast<const f32x4*>(trf + vid0 * 3);
    f32x4 t0 = tp[0], t1 = tp[1], t2 = tp[2];
    float d[12] = {t0.x, t0.y, t0.z, t0.w,
                   t1.x, t1.y, t1.z, t1.w,
                   t2.x, t2.y, t2.z, t2.w};

    const float mx = (float)(X - 1), my = (float)(Y - 1), mz = (float)(Z - 1);
    const float fx = (float)x, fy = (float)y;
    const int bX = b * X;

    float res[4];
#pragma unroll
    for (int e = 0; e < 4; ++e) {
        float lxf = fx + d[3 * e + 0];
        float lyf = fy + d[3 * e + 1];
        float lzf = (float)(z0v + e) + d[3 * e + 2];

        // reference semantics: l0=clip(floor(l),0,max); l1=clip(l0+1,0,max);
        // cl=clip(l,0,max); weight(corner0)=l1-cl; weight(corner1)=1-(l1-cl)
        float lx0 = fminf(fmaxf(floorf(lxf), 0.0f), mx);
        float lx1 = fminf(lx0 + 1.0f, mx);
        float clx = fminf(fmaxf(lxf, 0.0f), mx);
        float wxA = lx1 - clx, wxB = 1.0f - wxA;
        int ix0 = (int)lx0, ix1 = (int)lx1;

        float ly0 = fminf(fmaxf(floorf(lyf), 0.0f), my);
        float ly1 = fminf(ly0 + 1.0f, my);
        float cly = fminf(fmaxf(lyf, 0.0f), my);
        float wyA = ly1 - cly, wyB = 1.0f - wyA;
        int iy0 = (int)ly0, iy1 = (int)ly1;

        float lz0 = fminf(fmaxf(floorf(lzf), 0.0f), mz);
        float lz1 = fminf(lz0 + 1.0f, mz);
        float clz = fminf(fmaxf(lzf, 0.0f), mz);
        float wzA = lz1 - clz, wzB = 1.0f - wzA;
        int iz0 = (int)lz0, iz1 = (int)lz1;

        int ux0 = ix0 - xs, ux1 = ix1 - xs;
        int uy0 = iy0 - ys, uy1 = iy1 - ys;
        int uz0 = iz0 - zs, uz1 = iz1 - zs;

        bool ok = ((unsigned)ux0 < (unsigned)RX) & ((unsigned)ux1 < (unsigned)RX) &
                  ((unsigned)uy0 < (unsigned)RY) & ((unsigned)uy1 < (unsigned)RY) &
                  ((unsigned)uz0 < (unsigned)RZ) & ((unsigned)uz1 < (unsigned)RZ);

        float v000, v001, v010, v011, v100, v101, v110, v111;
        if (ok) {
            int r00 = (ux0 << 4) + uy0;
            int r01 = (ux0 << 4) + uy1;
            int r10 = (ux1 << 4) + uy0;
            int r11 = (ux1 << 4) + uy1;
            int m00 = (r00 & 7) << 2, m01 = (r01 & 7) << 2;
            int m10 = (r10 & 7) << 2, m11 = (r11 & 7) << 2;
            v000 = lds[(r00 << 5) + (uz0 ^ m00)];
            v001 = lds[(r00 << 5) + (uz1 ^ m00)];
            v010 = lds[(r01 << 5) + (uz0 ^ m01)];
            v011 = lds[(r01 << 5) + (uz1 ^ m01)];
            v100 = lds[(r10 << 5) + (uz0 ^ m10)];
            v101 = lds[(r10 << 5) + (uz1 ^ m10)];
            v110 = lds[(r11 << 5) + (uz0 ^ m11)];
            v111 = lds[(r11 << 5) + (uz1 ^ m11)];
        } else {
            size_t g00 = ((size_t)(bX + ix0) * Y + iy0) * Z;
            size_t g01 = ((size_t)(bX + ix0) * Y + iy1) * Z;
            size_t g10 = ((size_t)(bX + ix1) * Y + iy0) * Z;
            size_t g11 = ((size_t)(bX + ix1) * Y + iy1) * Z;
            v000 = vol[g00 + iz0];
            v001 = vol[g00 + iz1];
            v010 = vol[g01 + iz0];
            v011 = vol[g01 + iz1];
            v100 = vol[g10 + iz0];
            v101 = vol[g10 + iz1];
            v110 = vol[g11 + iz0];
            v111 = vol[g11 + iz1];
        }

        res[e] = wxA * (wyA * (wzA * v000 + wzB * v001) +
                        wyB * (wzA * v010 + wzB * v011)) +
                 wxB * (wyA * (wzA * v100 + wzB * v101) +
                        wyB * (wzA * v110 + wzB * v111));
    }

    f32x4 o;
    o.x = res[0]; o.y = res[1]; o.z = res[2]; o.w = res[3];
    *reinterpret_cast<f32x4*>(out + vid0) = o;
}

extern "C" void kernel_launch(void* const* d_in, const int* in_sizes, int n_in,
                              void* d_out, int out_size, void* d_ws, size_t ws_size,
                              hipStream_t stream) {
    const float* vol = (const float*)d_in[0];
    const float* trf = (const float*)d_in[1];
    float* out = (float*)d_out;

    warp_kernel<<<NTILES, 256, 0, stream>>>(vol, trf, out);
}

// Round 10
// 41.581 us; speedup vs baseline: 1.7748x; 1.1231x over previous
//
#include <hip/hip_runtime.h>

// vol [2,160,192,160,1] f32, trf [2,160,192,160,3] f32
constexpr int B = 2, X = 160, Y = 192, Z = 160;
constexpr int TXs = 8, TYs = 8, TZs = 16;                // output tile per block (1024 voxels)
constexpr int XT = X / TXs, YT = Y / TYs, ZT = Z / TZs;  // 20, 24, 10
constexpr int NTILES = B * XT * YT * ZT;                 // 9600, divisible by 8
constexpr int NXCD = 8;
constexpr int CHUNK = NTILES / NXCD;                     // 1200
// staged region: x,y halo +-4 (16 slots), z halo +-8 (32 slots)
constexpr int RX = 16, RY = 16, RZ = 32;
constexpr int NROWS = RX * RY;                           // 256 rows (row = xi*16+yi)
constexpr int RSTRIDE = RZ + 1;                          // 33 words: bank = (row+uz)%32
constexpr int LDSF = NROWS * RSTRIDE;                    // 8448 floats = 33792 B

typedef float f32x4 __attribute__((ext_vector_type(4)));
typedef float f32x2a __attribute__((ext_vector_type(2), aligned(4)));

__global__ __launch_bounds__(256) void warp_kernel(
    const float* __restrict__ vol,
    const float* __restrict__ trf,
    float* __restrict__ out)
{
    __shared__ float lds[LDSF];

    const int tid = threadIdx.x;
    const int bid = blockIdx.x;

    // XCD-chunked bijective swizzle (NTILES % 8 == 0)
    const int eff = (bid & (NXCD - 1)) * CHUNK + (bid >> 3);

    int tz = eff % ZT;
    int r  = eff / ZT;
    int ty = r % YT;
    int r2 = r / YT;
    int tx = r2 % XT;
    int b  = r2 / XT;

    const int xs = tx * TXs - 4;       // region x origin
    const int ys = ty * TYs - 4;       // region y origin
    const int zs = tz * TZs - 8;       // region z origin (multiple of 4)

    // ---- stage vol region into LDS; each 64B line walked once, coalesced ----
    // chunk c in [0,2048): row=c>>3 (xi=row>>4, yi=row&15), j=c&7 -> z=zs+4j
    // LDS addr = row*33 + 4j + i  (pad word per row spreads banks)
#pragma unroll
    for (int k = 0; k < 8; ++k) {
        int c   = tid + k * 256;
        int row = c >> 3;
        int j   = c & 7;
        int xi  = row >> 4;
        int yi  = row & 15;
        int xg  = min(max(xs + xi, 0), X - 1);
        int yg  = min(max(ys + yi, 0), Y - 1);
        int zg  = min(max(zs + 4 * j, 0), Z - 4);
        const f32x4 v = *reinterpret_cast<const f32x4*>(
            vol + ((size_t)(b * X + xg) * Y + yg) * Z + zg);
        int a = row * RSTRIDE + 4 * j;
        lds[a + 0] = v.x;
        lds[a + 1] = v.y;
        lds[a + 2] = v.z;
        lds[a + 3] = v.w;
    }
    __syncthreads();

    // ---- this thread's 4 voxels: (x, y, z0v..z0v+3) ----
    int zq = tid & 3;
    int ly = (tid >> 2) & 7;
    int lx = tid >> 5;
    int x  = tx * TXs + lx;
    int y  = ty * TYs + ly;
    int z0v = tz * TZs + 4 * zq;

    size_t vid0 = ((size_t)(b * X + x) * Y + y) * Z + z0v;

    const f32x4* tp = reinterpret_cast<const f32x4*>(trf + vid0 * 3);
    f32x4 t0 = tp[0], t1 = tp[1], t2 = tp[2];
    float d[12] = {t0.x, t0.y, t0.z, t0.w,
                   t1.x, t1.y, t1.z, t1.w,
                   t2.x, t2.y, t2.z, t2.w};

    const float mx = (float)(X - 1), my = (float)(Y - 1), mz = (float)(Z - 1);
    const float fx = (float)x, fy = (float)y;
    const int bX = b * X;

    float res[4];
#pragma unroll
    for (int e = 0; e < 4; ++e) {
        float lxf = fx + d[3 * e + 0];
        float lyf = fy + d[3 * e + 1];
        float lzf = (float)(z0v + e) + d[3 * e + 2];

        // reference semantics: l0=clip(floor(l),0,max); l1=clip(l0+1,0,max);
        // cl=clip(l,0,max); weight(corner0)=l1-cl; weight(corner1)=1-(l1-cl)
        float lx0 = fminf(fmaxf(floorf(lxf), 0.0f), mx);
        float lx1 = fminf(lx0 + 1.0f, mx);
        float clx = fminf(fmaxf(lxf, 0.0f), mx);
        float wxA = lx1 - clx, wxB = 1.0f - wxA;
        int ix0 = (int)lx0, ix1 = (int)lx1;

        float ly0 = fminf(fmaxf(floorf(lyf), 0.0f), my);
        float ly1 = fminf(ly0 + 1.0f, my);
        float cly = fminf(fmaxf(lyf, 0.0f), my);
        float wyA = ly1 - cly, wyB = 1.0f - wyA;
        int iy0 = (int)ly0, iy1 = (int)ly1;

        float lz0 = fminf(fmaxf(floorf(lzf), 0.0f), mz);
        float lz1 = fminf(lz0 + 1.0f, mz);
        float clz = fminf(fmaxf(lzf, 0.0f), mz);
        float wzA = lz1 - clz, wzB = 1.0f - wzA;
        int iz0 = (int)lz0, iz1 = (int)lz1;

        int ux0 = ix0 - xs, ux1 = ix1 - xs;
        int uy0 = iy0 - ys, uy1 = iy1 - ys;
        int uz0 = iz0 - zs, uz1 = iz1 - zs;

        bool ok = ((unsigned)ux0 < (unsigned)RX) & ((unsigned)ux1 < (unsigned)RX) &
                  ((unsigned)uy0 < (unsigned)RY) & ((unsigned)uy1 < (unsigned)RY) &
                  ((unsigned)uz0 < (unsigned)RZ) & ((unsigned)uz1 < (unsigned)RZ);

        float v000, v001, v010, v011, v100, v101, v110, v111;
        if (ok) {
            // z-pair reads: slots uz0, uz0+1 are contiguous; when iz1==iz0
            // (z edge) take .x for both. In the ok path uz0 <= 30, so the
            // pair never touches the pad word.
            bool edge = (iz1 == iz0);
            int r00 = ((ux0 << 4) + uy0) * RSTRIDE + uz0;
            int r01 = ((ux0 << 4) + uy1) * RSTRIDE + uz0;
            int r10 = ((ux1 << 4) + uy0) * RSTRIDE + uz0;
            int r11 = ((ux1 << 4) + uy1) * RSTRIDE + uz0;
            f32x2a p00 = *reinterpret_cast<const f32x2a*>(&lds[r00]);
            f32x2a p01 = *reinterpret_cast<const f32x2a*>(&lds[r01]);
            f32x2a p10 = *reinterpret_cast<const f32x2a*>(&lds[r10]);
            f32x2a p11 = *reinterpret_cast<const f32x2a*>(&lds[r11]);
            v000 = p00.x; v001 = edge ? p00.x : p00.y;
            v010 = p01.x; v011 = edge ? p01.x : p01.y;
            v100 = p10.x; v101 = edge ? p10.x : p10.y;
            v110 = p11.x; v111 = edge ? p11.x : p11.y;
        } else {
            size_t g00 = ((size_t)(bX + ix0) * Y + iy0) * Z;
            size_t g01 = ((size_t)(bX + ix0) * Y + iy1) * Z;
            size_t g10 = ((size_t)(bX + ix1) * Y + iy0) * Z;
            size_t g11 = ((size_t)(bX + ix1) * Y + iy1) * Z;
            v000 = vol[g00 + iz0];
            v001 = vol[g00 + iz1];
            v010 = vol[g01 + iz0];
            v011 = vol[g01 + iz1];
            v100 = vol[g10 + iz0];
            v101 = vol[g10 + iz1];
            v110 = vol[g11 + iz0];
            v111 = vol[g11 + iz1];
        }

        res[e] = wxA * (wyA * (wzA * v000 + wzB * v001) +
                        wyB * (wzA * v010 + wzB * v011)) +
                 wxB * (wyA * (wzA * v100 + wzB * v101) +
                        wyB * (wzA * v110 + wzB * v111));
    }

    f32x4 o;
    o.x = res[0]; o.y = res[1]; o.z = res[2]; o.w = res[3];
    *reinterpret_cast<f32x4*>(out + vid0) = o;
}

extern "C" void kernel_launch(void* const* d_in, const int* in_sizes, int n_in,
                              void* d_out, int out_size, void* d_ws, size_t ws_size,
                              hipStream_t stream) {
    const float* vol = (const float*)d_in[0];
    const float* trf = (const float*)d_in[1];
    float* out = (float*)d_out;

    warp_kernel<<<NTILES, 256, 0, stream>>>(vol, trf, out);
}

// Round 11
// 40.396 us; speedup vs baseline: 1.8268x; 1.0293x over previous
//
#include <hip/hip_runtime.h>

// vol [2,160,192,160,1] f32, trf [2,160,192,160,3] f32
constexpr int B = 2, X = 160, Y = 192, Z = 160;
constexpr int TXs = 8, TYs = 8, TZs = 16;                // output tile per block (1024 voxels)
constexpr int XT = X / TXs, YT = Y / TYs, ZT = Z / TZs;  // 20, 24, 10
constexpr int NTILES = B * XT * YT * ZT;                 // 9600, divisible by 8
constexpr int NXCD = 8;
constexpr int CHUNK = NTILES / NXCD;                     // 1200
// staged region: x,y halo +-4 (16 slots), z halo +-4 (24 slots)
constexpr int RX = 16, RY = 16, RZ = 24;
constexpr int NROWS = RX * RY;                           // 256 rows (row = xi*16+yi)
constexpr int RSTRIDE = RZ + 1;                          // 25 words (odd): bank spread, pad never read
constexpr int LDSF = NROWS * RSTRIDE;                    // 6400 floats = 25600 B -> 6 blocks/CU

typedef float f32x4 __attribute__((ext_vector_type(4)));
typedef float f32x2a __attribute__((ext_vector_type(2), aligned(4)));

__global__ __launch_bounds__(256, 6) void warp_kernel(
    const float* __restrict__ vol,
    const float* __restrict__ trf,
    float* __restrict__ out)
{
    __shared__ float lds[LDSF];

    const int tid = threadIdx.x;
    const int bid = blockIdx.x;

    // XCD-chunked bijective swizzle (NTILES % 8 == 0)
    const int eff = (bid & (NXCD - 1)) * CHUNK + (bid >> 3);

    int tz = eff % ZT;
    int r  = eff / ZT;
    int ty = r % YT;
    int r2 = r / YT;
    int tx = r2 % XT;
    int b  = r2 / XT;

    const int xs = tx * TXs - 4;       // region x origin
    const int ys = ty * TYs - 4;       // region y origin
    const int zs = tz * TZs - 4;       // region z origin (multiple of 4)

    // ---- stage vol region into LDS ----
    // 1536 f32x4 chunks: chunk c -> row = c/6 (xi=row>>4, yi=row&15), j = c%6, z = zs+4j.
    // Thread handles c = tid + 256k, k<6; (row,j) advanced incrementally:
    // +256 chunks = +42 rows, j += 4 (mod 6, carry into row).
    {
        int row = (tid * 171) >> 10;       // tid / 6 (exact for tid < 1024)
        int j   = tid - 6 * row;
#pragma unroll
        for (int k = 0; k < 6; ++k) {
            int xi = row >> 4;
            int yi = row & 15;
            int xg = min(max(xs + xi, 0), X - 1);
            int yg = min(max(ys + yi, 0), Y - 1);
            int zg = min(max(zs + 4 * j, 0), Z - 4);
            const f32x4 v = *reinterpret_cast<const f32x4*>(
                vol + ((size_t)(b * X + xg) * Y + yg) * Z + zg);
            int a = row * RSTRIDE + 4 * j;
            lds[a + 0] = v.x;
            lds[a + 1] = v.y;
            lds[a + 2] = v.z;
            lds[a + 3] = v.w;
            int jn = j + 4;
            bool wrap = (jn >= 6);
            j   = wrap ? jn - 6 : jn;
            row += wrap ? 43 : 42;
        }
    }
    __syncthreads();

    // ---- this thread's 4 voxels: (x, y, z0v..z0v+3) ----
    int zq = tid & 3;
    int ly = (tid >> 2) & 7;
    int lx = tid >> 5;
    int x  = tx * TXs + lx;
    int y  = ty * TYs + ly;
    int z0v = tz * TZs + 4 * zq;

    size_t vid0 = ((size_t)(b * X + x) * Y + y) * Z + z0v;

    const f32x4* tp = reinterpret_cast<const f32x4*>(trf + vid0 * 3);
    f32x4 t0 = tp[0], t1 = tp[1], t2 = tp[2];
    float d[12] = {t0.x, t0.y, t0.z, t0.w,
                   t1.x, t1.y, t1.z, t1.w,
                   t2.x, t2.y, t2.z, t2.w};

    const float mx = (float)(X - 1), my = (float)(Y - 1), mz = (float)(Z - 1);
    const float fx = (float)x, fy = (float)y;
    const int bX = b * X;

    float res[4];
#pragma unroll
    for (int e = 0; e < 4; ++e) {
        float lxf = fx + d[3 * e + 0];
        float lyf = fy + d[3 * e + 1];
        float lzf = (float)(z0v + e) + d[3 * e + 2];

        // reference semantics: l0=clip(floor(l),0,max); l1=clip(l0+1,0,max);
        // cl=clip(l,0,max); weight(corner0)=l1-cl; weight(corner1)=1-(l1-cl)
        float lx0 = fminf(fmaxf(floorf(lxf), 0.0f), mx);
        float lx1 = fminf(lx0 + 1.0f, mx);
        float clx = fminf(fmaxf(lxf, 0.0f), mx);
        float wxA = lx1 - clx, wxB = 1.0f - wxA;
        int ix0 = (int)lx0, ix1 = (int)lx1;

        float ly0 = fminf(fmaxf(floorf(lyf), 0.0f), my);
        float ly1 = fminf(ly0 + 1.0f, my);
        float cly = fminf(fmaxf(lyf, 0.0f), my);
        float wyA = ly1 - cly, wyB = 1.0f - wyA;
        int iy0 = (int)ly0, iy1 = (int)ly1;

        float lz0 = fminf(fmaxf(floorf(lzf), 0.0f), mz);
        float lz1 = fminf(lz0 + 1.0f, mz);
        float clz = fminf(fmaxf(lzf, 0.0f), mz);
        float wzA = lz1 - clz, wzB = 1.0f - wzA;
        int iz0 = (int)lz0, iz1 = (int)lz1;

        // z top-edge (iz1==iz0==Z-1): weight moves entirely to corner1; the
        // "+1" LDS slot is then garbage. Flip weights so corner0 (valid slot)
        // carries weight 1 and corner1 is multiplied by 0 (inputs finite).
        bool edge = (iz1 == iz0);
        float wzAe = edge ? 1.0f : wzA;
        float wzBe = edge ? 0.0f : wzB;

        int ux0 = ix0 - xs, ux1 = ix1 - xs;
        int uy0 = iy0 - ys, uy1 = iy1 - ys;
        int uz0 = iz0 - zs;

        // uz1 = uz0+1 <= RZ-1 iff uz0 < RZ-1; pair-read never touches pad.
        bool ok = ((unsigned)ux0 < (unsigned)RX) & ((unsigned)ux1 < (unsigned)RX) &
                  ((unsigned)uy0 < (unsigned)RY) & ((unsigned)uy1 < (unsigned)RY) &
                  ((unsigned)uz0 < (unsigned)(RZ - 1));

        float v000, v001, v010, v011, v100, v101, v110, v111;
        if (ok) {
            int dY  = (iy1 > iy0) ? RSTRIDE : 0;
            int dXx = (ix1 > ix0) ? (RSTRIDE * 16) : 0;
            int r00 = ((ux0 << 4) + uy0) * RSTRIDE + uz0;
            int r01 = r00 + dY;
            int r10 = r00 + dXx;
            int r11 = r10 + dY;
            f32x2a p00 = *reinterpret_cast<const f32x2a*>(&lds[r00]);
            f32x2a p01 = *reinterpret_cast<const f32x2a*>(&lds[r01]);
            f32x2a p10 = *reinterpret_cast<const f32x2a*>(&lds[r10]);
            f32x2a p11 = *reinterpret_cast<const f32x2a*>(&lds[r11]);
            v000 = p00.x; v001 = p00.y;
            v010 = p01.x; v011 = p01.y;
            v100 = p10.x; v101 = p10.y;
            v110 = p11.x; v111 = p11.y;
        } else {
            size_t g00 = ((size_t)(bX + ix0) * Y + iy0) * Z;
            size_t g01 = ((size_t)(bX + ix0) * Y + iy1) * Z;
            size_t g10 = ((size_t)(bX + ix1) * Y + iy0) * Z;
            size_t g11 = ((size_t)(bX + ix1) * Y + iy1) * Z;
            v000 = vol[g00 + iz0];
            v001 = vol[g00 + iz1];
            v010 = vol[g01 + iz0];
            v011 = vol[g01 + iz1];
            v100 = vol[g10 + iz0];
            v101 = vol[g10 + iz1];
            v110 = vol[g11 + iz0];
            v111 = vol[g11 + iz1];
        }

        res[e] = wxA * (wyA * (wzAe * v000 + wzBe * v001) +
                        wyB * (wzAe * v010 + wzBe * v011)) +
                 wxB * (wyA * (wzAe * v100 + wzBe * v101) +
                        wyB * (wzAe * v110 + wzBe * v111));
    }

    f32x4 o;
    o.x = res[0]; o.y = res[1]; o.z = res[2]; o.w = res[3];
    *reinterpret_cast<f32x4*>(out + vid0) = o;
}

extern "C" void kernel_launch(void* const* d_in, const int* in_sizes, int n_in,
                              void* d_out, int out_size, void* d_ws, size_t ws_size,
                              hipStream_t stream) {
    const float* vol = (const float*)d_in[0];
    const float* trf = (const float*)d_in[1];
    float* out = (float*)d_out;

    warp_kernel<<<NTILES, 256, 0, stream>>>(vol, trf, out);
}